// Round 1
// baseline (523.759 us; speedup 1.0000x reference)
//
#include <hip/hip_runtime.h>
#include <stdint.h>

// WindowedAttn on MI355X (gfx950)
// Pipeline: cast x->bf16 | transpose W_qkv,W_out -> bf16 B^T | GEMM1 (qkv, bf16 out)
//           | flash attention per 128-q tile (S^T / O^T trick) | GEMM2 (fp32 out)
// GEMMs: 128x128 block tile, BK=64, global_load_lds width=16, XOR-swizzled LDS
// (chunk ^ (row&7)) -> conflict-free ds_read_b128 (vs m97's 8-way).

typedef unsigned short u16;
typedef unsigned int u32;
typedef __attribute__((ext_vector_type(8))) short bf16x8;   // 8 bf16 = 4 VGPRs
typedef __attribute__((ext_vector_type(4))) float f32x4;

#define QKVN 6144
#define DM 2048

__device__ __forceinline__ u16 f2b(float f) {
  u32 u = __builtin_bit_cast(u32, f);
  u32 r = (u + 0x7fffu + ((u >> 16) & 1u)) >> 16;  // RNE
  return (u16)r;
}

__device__ __forceinline__ void gload_lds16(const void* g, void* l) {
  __builtin_amdgcn_global_load_lds((const __attribute__((address_space(1))) void*)g,
                                   (__attribute__((address_space(3))) void*)l,
                                   16, 0, 0);
}

// ---------------- prep kernels ----------------

__global__ void cast_f32_bf16(const float4* __restrict__ x, uint4* __restrict__ o) {
  int idx = blockIdx.x * 256 + threadIdx.x;   // grid sized exactly: n/8 threads
  float4 a = x[2 * idx];
  float4 b = x[2 * idx + 1];
  uint4 r;
  r.x = (u32)f2b(a.x) | ((u32)f2b(a.y) << 16);
  r.y = (u32)f2b(a.z) | ((u32)f2b(a.w) << 16);
  r.z = (u32)f2b(b.x) | ((u32)f2b(b.y) << 16);
  r.w = (u32)f2b(b.z) | ((u32)f2b(b.w) << 16);
  o[idx] = r;
}

// W (K x N, fp32, row-major) -> Wt (N x K, bf16, row-major)
__global__ void transpose_cast(const float* __restrict__ W, u16* __restrict__ Wt,
                               int K, int N) {
  __shared__ u16 tile[64][65];
  int tx = threadIdx.x & 63;
  int ty = threadIdx.x >> 6;
  int n0 = blockIdx.x * 64;
  int k0 = blockIdx.y * 64;
#pragma unroll
  for (int r = 0; r < 64; r += 4)
    tile[r + ty][tx] = f2b(W[(size_t)(k0 + r + ty) * N + n0 + tx]);
  __syncthreads();
#pragma unroll
  for (int r = 0; r < 64; r += 4)
    Wt[(size_t)(n0 + r + ty) * K + k0 + tx] = tile[tx][r + ty];
}

// ---------------- GEMM: C[M][N] = A[M][K] * Bt[N][K]^T + bias ----------------
// block 256 = 4 waves (2x2 of 64x64), 4x4 16x16x32 mfma per wave

template <typename TO>
__global__ __launch_bounds__(256, 3) void gemm_bt(const u16* __restrict__ A,
                                                  const u16* __restrict__ Bt,
                                                  const float* __restrict__ bias,
                                                  TO* __restrict__ C,
                                                  int M, int N, int K) {
  __shared__ u16 As[128 * 64];
  __shared__ u16 Bs[128 * 64];
  const int tid = threadIdx.x;
  const int lane = tid & 63;
  const int wave = tid >> 6;
  const int quad = lane >> 4;
  const int l15 = lane & 15;
  const int m0 = blockIdx.y * 128;
  const int n0 = blockIdx.x * 128;
  const int wm = (wave & 1) * 64;
  const int wn = (wave >> 1) * 64;

  f32x4 acc[4][4] = {};

  for (int k0 = 0; k0 < K; k0 += 64) {
    // stage A,B tiles: row = 128B = 8 chunks of 16B; stored chunk c' = c ^ (row&7)
#pragma unroll
    for (int i = 0; i < 4; ++i) {
      int sb = wave * 256 + i * 64;     // wave-uniform slot base
      int s = sb + lane;                // slot = row*8 + c'
      int m = s >> 3;
      int c = (s & 7) ^ (m & 7);        // global chunk to fetch for this slot
      gload_lds16(A + (size_t)(m0 + m) * K + (k0 + c * 8), As + sb * 8);
      gload_lds16(Bt + (size_t)(n0 + m) * K + (k0 + c * 8), Bs + sb * 8);
    }
    __syncthreads();
#pragma unroll
    for (int ks = 0; ks < 2; ++ks) {
      bf16x8 af[4], bf[4];
#pragma unroll
      for (int i = 0; i < 4; ++i) {
        int m = wm + i * 16 + l15;
        af[i] = *(const bf16x8*)(As + m * 64 + (((ks * 4 + quad) ^ (m & 7)) << 3));
        int n = wn + i * 16 + l15;
        bf[i] = *(const bf16x8*)(Bs + n * 64 + (((ks * 4 + quad) ^ (n & 7)) << 3));
      }
#pragma unroll
      for (int i = 0; i < 4; ++i)
#pragma unroll
        for (int j = 0; j < 4; ++j)
          acc[i][j] = __builtin_amdgcn_mfma_f32_16x16x32_bf16(af[i], bf[j], acc[i][j], 0, 0, 0);
    }
    __syncthreads();
  }

  // epilogue: D row=(quad*4+t), col=l15 (m89-verified)
#pragma unroll
  for (int j = 0; j < 4; ++j) {
    int col = n0 + wn + j * 16 + l15;
    float bv = bias[col];
#pragma unroll
    for (int i = 0; i < 4; ++i) {
      int row = m0 + wm + i * 16 + quad * 4;
#pragma unroll
      for (int t = 0; t < 4; ++t) {
        float v = acc[i][j][t] + bv;
        if constexpr (sizeof(TO) == 2)
          C[(size_t)(row + t) * N + col] = (TO)f2b(v);
        else
          C[(size_t)(row + t) * N + col] = (TO)v;
      }
    }
  }
}

// ---------------- attention ----------------
// One block per (b, h, win, qtile of 128). kk-tiles of 64.
// S^T = K * Q^T  (A-frag: K rows from global; B-frag: Q rows from global)
// O^T += V^T * P^T (A-frag: Vt LDS [d][kk]; B-frag: Ps LDS [q][kk]) -- both XOR-swizzled.

__global__ __launch_bounds__(256, 2) void attn_win(const u16* __restrict__ qkv,
                                                   u16* __restrict__ attn_out) {
  __shared__ u16 Vt[128 * 64];  // [d][kk], chunk ^ (d&7)
  __shared__ u16 Ps[128 * 64];  // [q][kk], chunk ^ (q&7)
  const int tid = threadIdx.x;
  const int lane = tid & 63;
  const int wave = tid >> 6;
  const int quad = lane >> 4;
  const int l15 = lane & 15;
  const int qt = blockIdx.x;        // 0..3
  const int win = blockIdx.y;       // 0..7
  const int b = blockIdx.z >> 4;
  const int h = blockIdx.z & 15;
  const int tokw = b * 4096 + win * 512;
  const int tokq = tokw + qt * 128;
  const float SCALE = 0.08838834764831845f;

  // Q fragments (kept in registers for the whole block)
  bf16x8 qf[2][4];
  {
    const u16* Qb = qkv + (size_t)tokq * QKVN + h * 128;
#pragma unroll
    for (int j = 0; j < 2; ++j) {
      const u16* Qr = Qb + (size_t)(wave * 32 + j * 16 + l15) * QKVN + quad * 8;
#pragma unroll
      for (int ks = 0; ks < 4; ++ks)
        qf[j][ks] = *(const bf16x8*)(Qr + ks * 32);
    }
  }

  f32x4 acc_o[8][2] = {};
  float mrun[2] = {-1e30f, -1e30f};
  float lrun[2] = {0.f, 0.f};

  const int jt_end = 2 * qt + 1;
  for (int jt = 0; jt <= jt_end; ++jt) {
    // ---- stage V^T into LDS (transpose during write, pairwise packed) ----
    {
      const u16* Vb = qkv + (size_t)(tokw + jt * 64) * QKVN + 4096 + h * 128;
#pragma unroll
      for (int it = 0; it < 2; ++it) {
        int task = it * 256 + tid;    // 512 tasks: 16 d-chunks x 32 kk-pairs
        int p = task & 31;
        int dc = task >> 5;
        int kk0 = p * 2;
        const u16* g0 = Vb + (size_t)kk0 * QKVN + dc * 8;
        uint4 r0 = *(const uint4*)g0;
        uint4 r1 = *(const uint4*)(g0 + QKVN);
        const u16* a0 = (const u16*)&r0;
        const u16* a1 = (const u16*)&r1;
        int c = kk0 >> 3;
        int boff = (kk0 & 7) << 1;
#pragma unroll
        for (int j = 0; j < 8; ++j) {
          int d = dc * 8 + j;
          *(u32*)((char*)Vt + d * 128 + ((c ^ (d & 7)) << 4) + boff) =
              (u32)a0[j] | ((u32)a1[j] << 16);
        }
      }
    }

    // ---- S^T = K * Q^T ----
    f32x4 acc_s[4][2] = {};
    {
      const u16* Kb = qkv + (size_t)(tokw + jt * 64) * QKVN + 2048 + h * 128;
      bf16x8 kf[4][4];
#pragma unroll
      for (int i = 0; i < 4; ++i) {
        const u16* Kr = Kb + (size_t)(i * 16 + l15) * QKVN + quad * 8;
#pragma unroll
        for (int ks = 0; ks < 4; ++ks)
          kf[i][ks] = *(const bf16x8*)(Kr + ks * 32);
      }
#pragma unroll
      for (int ks = 0; ks < 4; ++ks)
#pragma unroll
        for (int i = 0; i < 4; ++i)
#pragma unroll
          for (int j = 0; j < 2; ++j)
            acc_s[i][j] = __builtin_amdgcn_mfma_f32_16x16x32_bf16(kf[i][ks], qf[j][ks],
                                                                  acc_s[i][j], 0, 0, 0);
    }

    // ---- online softmax (per-lane state; q fixed per lane) ----
    const bool need_mask = (jt >= 2 * qt);
#pragma unroll
    for (int j = 0; j < 2; ++j) {
      int ql = wave * 32 + j * 16 + l15;  // q local in 128-tile
      int qg = qt * 128 + ql;             // q in window
      float vmax = -1e30f;
#pragma unroll
      for (int i = 0; i < 4; ++i)
#pragma unroll
        for (int t = 0; t < 4; ++t) {
          float s = acc_s[i][j][t] * SCALE;
          if (need_mask) {
            int kg = jt * 64 + i * 16 + quad * 4 + t;
            if (kg > qg) s = -1e30f;
          }
          acc_s[i][j][t] = s;
          vmax = fmaxf(vmax, s);
        }
      vmax = fmaxf(vmax, __shfl_xor(vmax, 16));
      vmax = fmaxf(vmax, __shfl_xor(vmax, 32));
      float mnew = fmaxf(mrun[j], vmax);
      float alpha = __expf(mrun[j] - mnew);
      mrun[j] = mnew;
      float vsum = 0.f;
#pragma unroll
      for (int i = 0; i < 4; ++i) {
        float p0 = __expf(acc_s[i][j][0] - mnew);
        float p1 = __expf(acc_s[i][j][1] - mnew);
        float p2 = __expf(acc_s[i][j][2] - mnew);
        float p3 = __expf(acc_s[i][j][3] - mnew);
        vsum += (p0 + p1) + (p2 + p3);
        uint2 pk;
        pk.x = (u32)f2b(p0) | ((u32)f2b(p1) << 16);
        pk.y = (u32)f2b(p2) | ((u32)f2b(p3) << 16);
        int kk = i * 16 + quad * 4;
        *(uint2*)((char*)Ps + ql * 128 + (((kk >> 3) ^ (ql & 7)) << 4) + ((kk & 7) << 1)) = pk;
      }
      vsum += __shfl_xor(vsum, 16);
      vsum += __shfl_xor(vsum, 32);
      lrun[j] = lrun[j] * alpha + vsum;
#pragma unroll
      for (int i2 = 0; i2 < 8; ++i2)
#pragma unroll
        for (int t = 0; t < 4; ++t)
          acc_o[i2][j][t] *= alpha;
    }
    __syncthreads();  // Vt staged + Ps written

    // ---- O^T += V^T * P^T ----
#pragma unroll
    for (int ks = 0; ks < 2; ++ks) {
      int kk = ks * 32 + quad * 8;
      int kc = kk >> 3;
      bf16x8 pf[2];
#pragma unroll
      for (int j = 0; j < 2; ++j) {
        int ql = wave * 32 + j * 16 + l15;
        pf[j] = *(const bf16x8*)((char*)Ps + ql * 128 + ((kc ^ (ql & 7)) << 4));
      }
#pragma unroll
      for (int i2 = 0; i2 < 8; ++i2) {
        int d = i2 * 16 + l15;
        bf16x8 vf = *(const bf16x8*)((char*)Vt + d * 128 + ((kc ^ (d & 7)) << 4));
#pragma unroll
        for (int j = 0; j < 2; ++j)
          acc_o[i2][j] = __builtin_amdgcn_mfma_f32_16x16x32_bf16(vf, pf[j], acc_o[i2][j], 0, 0, 0);
      }
    }
    __syncthreads();  // protect Vt/Ps for next jt
  }

  // ---- epilogue: O^T C-layout -> attn_out[tok][h*128+d], 4 contiguous d per store ----
#pragma unroll
  for (int j = 0; j < 2; ++j) {
    float inv = 1.0f / lrun[j];
    int ql = wave * 32 + j * 16 + l15;
    u16* orow = attn_out + (size_t)(tokq + ql) * DM + h * 128;
#pragma unroll
    for (int i2 = 0; i2 < 8; ++i2) {
      int d = i2 * 16 + quad * 4;
      uint2 pk;
      pk.x = (u32)f2b(acc_o[i2][j][0] * inv) | ((u32)f2b(acc_o[i2][j][1] * inv) << 16);
      pk.y = (u32)f2b(acc_o[i2][j][2] * inv) | ((u32)f2b(acc_o[i2][j][3] * inv) << 16);
      *(uint2*)(orow + d) = pk;
    }
  }
}

// ---------------- launch ----------------

extern "C" void kernel_launch(void* const* d_in, const int* in_sizes, int n_in,
                              void* d_out, int out_size, void* d_ws, size_t ws_size,
                              hipStream_t stream) {
  const float* x = (const float*)d_in[0];
  const float* W_qkv = (const float*)d_in[1];
  const float* b_qkv = (const float*)d_in[2];
  const float* W_out = (const float*)d_in[3];
  const float* b_out = (const float*)d_in[4];
  float* out = (float*)d_out;

  char* w = (char*)d_ws;
  u16* xb = (u16*)w;                                   // 32MB [8192][2048]; reused as attn_out
  u16* wqkvT = (u16*)(w + 33554432);                   // 24MB [6144][2048]
  u16* woutT = (u16*)(w + 33554432 + 25165824);        // 8MB  [2048][2048]
  u16* qkv = (u16*)(w + 67108864);                     // 96MB [8192][6144]

  cast_f32_bf16<<<8192, 256, 0, stream>>>((const float4*)x, (uint4*)xb);
  transpose_cast<<<dim3(96, 32), 256, 0, stream>>>(W_qkv, wqkvT, 2048, 6144);
  transpose_cast<<<dim3(32, 32), 256, 0, stream>>>(W_out, woutT, 2048, 2048);
  gemm_bt<u16><<<dim3(48, 64), 256, 0, stream>>>(xb, wqkvT, b_qkv, qkv, 8192, 6144, 2048);
  attn_win<<<dim3(4, 8, 32), 256, 0, stream>>>(qkv, xb);
  gemm_bt<float><<<dim3(16, 64), 256, 0, stream>>>(xb, woutT, b_out, out, 8192, 2048, 2048);
}